// Round 2
// baseline (2759.575 us; speedup 1.0000x reference)
//
#include <hip/hip_runtime.h>

typedef __attribute__((ext_vector_type(8))) short short8;
typedef __attribute__((ext_vector_type(4))) float f32x4;

#define AS1 __attribute__((address_space(1)))
#define AS3 __attribute__((address_space(3)))

__device__ __forceinline__ void async_cp16(void* lds_dst, const void* g_src) {
  __builtin_amdgcn_global_load_lds((const AS1 void*)g_src, (AS3 void*)lds_dst, 16, 0, 0);
}

__device__ __forceinline__ unsigned short f2bf(float f) {
  unsigned int x = __float_as_uint(f);
  x += 0x7FFFu + ((x >> 16) & 1u);
  return (unsigned short)(x >> 16);
}

// ---------------- pass 1: sum(|w|) per weight matrix ----------------
__global__ void k_absmean(const float4* __restrict__ w, int n4, double* __restrict__ out) {
  double s = 0.0;
  int stride = gridDim.x * blockDim.x;
  for (int i = blockIdx.x * blockDim.x + threadIdx.x; i < n4; i += stride) {
    float4 v = w[i];
    s += (double)(fabsf(v.x) + fabsf(v.y) + fabsf(v.z) + fabsf(v.w));
  }
  for (int off = 32; off > 0; off >>= 1) s += __shfl_down(s, off);
  __shared__ double ss[4];
  int lane = threadIdx.x & 63, wid = threadIdx.x >> 6;
  if (lane == 0) ss[wid] = s;
  __syncthreads();
  if (threadIdx.x == 0) atomicAdd(out, ss[0] + ss[1] + ss[2] + ss[3]);
}

// ---------------- pass 2a: ternary-quantize -> DENSE bf16 in ws ----------------
__global__ void k_quant_w_dense(const float* __restrict__ w, unsigned short* __restrict__ dst,
                                int nchunks, const double* __restrict__ sum, double inv_n) {
  float thr = (float)(*sum * 0.7 * inv_n);
  int stride = gridDim.x * blockDim.x;
  const float4* w4 = (const float4*)w;
  for (int c = blockIdx.x * blockDim.x + threadIdx.x; c < nchunks; c += stride) {
    float4 a = w4[(size_t)c * 2], b = w4[(size_t)c * 2 + 1];
    float v[8] = {a.x, a.y, a.z, a.w, b.x, b.y, b.z, b.w};
    short8 o;
#pragma unroll
    for (int e = 0; e < 8; e++) {
      unsigned int bits = __float_as_uint(v[e]);
      unsigned short q = (fabsf(v[e]) > thr)
                             ? (unsigned short)(0x3F80u | ((bits >> 16) & 0x8000u))
                             : (unsigned short)0;
      o[e] = (short)q;
    }
    *(short8*)(dst + (size_t)c * 8) = o;
  }
}

// ---------------- pass 2b (fallback): quantize IN-PLACE, chunked ----------------
// chunk c (8 elements) -> 8 bf16 packed in bytes [32c, 32c+16); write range is a
// subset of the thread's own read range -> race-free.
__global__ void k_quant_w_inplace(float* __restrict__ w, int nchunks,
                                  const double* __restrict__ sum, double inv_n) {
  float thr = (float)(*sum * 0.7 * inv_n);
  int stride = gridDim.x * blockDim.x;
  for (int c = blockIdx.x * blockDim.x + threadIdx.x; c < nchunks; c += stride) {
    const float4* src = (const float4*)((const char*)w + (size_t)c * 32);
    float4 a = src[0], b = src[1];
    float v[8] = {a.x, a.y, a.z, a.w, b.x, b.y, b.z, b.w};
    short8 o;
#pragma unroll
    for (int e = 0; e < 8; e++) {
      unsigned int bits = __float_as_uint(v[e]);
      unsigned short q = (fabsf(v[e]) > thr)
                             ? (unsigned short)(0x3F80u | ((bits >> 16) & 0x8000u))
                             : (unsigned short)0;
      o[e] = (short)q;
    }
    *(short8*)((char*)w + (size_t)c * 32) = o;
  }
}

// ---------------- pass 3: x -> contiguous bf16 ----------------
__global__ void k_quant_x(const float4* __restrict__ x, unsigned short* __restrict__ xq,
                          int nchunks) {
  int stride = gridDim.x * blockDim.x;
  for (int c = blockIdx.x * blockDim.x + threadIdx.x; c < nchunks; c += stride) {
    float4 a = x[(size_t)c * 2], b = x[(size_t)c * 2 + 1];
    float v[8] = {a.x, a.y, a.z, a.w, b.x, b.y, b.z, b.w};
    short8 o;
#pragma unroll
    for (int e = 0; e < 8; e++) o[e] = (short)f2bf(v[e]);
    *(short8*)(xq + (size_t)c * 8) = o;
  }
}

// ---------------- GEMM1: gate+up fused, SiLU epilogue -> hidden bf16 ----------------
// A: xq [4096][4096] bf16 contiguous (row stride 8192 B, chunk stride 16 B).
// B (gate/up): row stride bRow bytes, k-chunk c at byte c*bChunk (16 B payload),
// per-K-step advance bStep bytes. Dense: (8192,16,64). Chunked: (16384,32,128).
__global__ __launch_bounds__(256, 2) void k_mlp_gemm1(
    const char* __restrict__ xq, const char* __restrict__ gw, const char* __restrict__ uw,
    const float* __restrict__ gscale, const float* __restrict__ uscale,
    unsigned short* __restrict__ hidden, size_t bRow, int bChunk, int bStep) {
  __shared__ __align__(16) unsigned short sA[4096], sG[4096], sU[4096];
  const int tid = threadIdx.x, lane = tid & 63, wid = tid >> 6;
  const int mt = blockIdx.x & 31, nt = blockIdx.x >> 5;  // mt-inner: 32 blocks share B panel
  const size_t m0 = (size_t)mt * 128, n0 = (size_t)nt * 128;

  // staging: LDS slot q (16B) holds row r=q>>2, source k-chunk (q&3)^((r>>1)&3)
  const int q0 = wid * 64 + lane, q1 = q0 + 256;
  const int r0 = q0 >> 2, c0 = (q0 & 3) ^ ((q0 >> 3) & 3);
  const int r1 = q1 >> 2, c1 = (q1 & 3) ^ ((q1 >> 3) & 3);

  const char* srcA0 = xq + (m0 + r0) * 8192 + c0 * 16;
  const char* srcA1 = xq + (m0 + r1) * 8192 + c1 * 16;
  const char* srcG0 = gw + (n0 + r0) * bRow + (size_t)c0 * bChunk;
  const char* srcG1 = gw + (n0 + r1) * bRow + (size_t)c1 * bChunk;
  const char* srcU0 = uw + (n0 + r0) * bRow + (size_t)c0 * bChunk;
  const char* srcU1 = uw + (n0 + r1) * bRow + (size_t)c1 * bChunk;

  char* dA0 = (char*)sA + wid * 1024; char* dA1 = dA0 + 4096;
  char* dG0 = (char*)sG + wid * 1024; char* dG1 = dG0 + 4096;
  char* dU0 = (char*)sU + wid * 1024; char* dU1 = dU0 + 4096;

  const int wm = wid >> 1, wn = wid & 1, ln = lane & 15;
  const int slot = ((lane >> 4) ^ ((ln >> 1) & 3)) * 16;  // inverts staged permutation
  const char* aBase = (const char*)sA + (size_t)(wm * 64 + ln) * 64 + slot;
  const char* gBase = (const char*)sG + (size_t)(wn * 64 + ln) * 64 + slot;
  const char* uBase = (const char*)sU + (size_t)(wn * 64 + ln) * 64 + slot;

  f32x4 accg[4][4] = {}; f32x4 accu[4][4] = {};

  for (int kt = 0; kt < 4096; kt += 32) {
    async_cp16(dA0, srcA0); async_cp16(dA1, srcA1);
    async_cp16(dG0, srcG0); async_cp16(dG1, srcG1);
    async_cp16(dU0, srcU0); async_cp16(dU1, srcU1);
    srcA0 += 64; srcA1 += 64;
    srcG0 += bStep; srcG1 += bStep; srcU0 += bStep; srcU1 += bStep;
    __syncthreads();
    short8 a[4], bg[4], bu[4];
#pragma unroll
    for (int i = 0; i < 4; i++) {
      a[i]  = *(const short8*)(aBase + i * 1024);
      bg[i] = *(const short8*)(gBase + i * 1024);
      bu[i] = *(const short8*)(uBase + i * 1024);
    }
#pragma unroll
    for (int i = 0; i < 4; i++)
#pragma unroll
      for (int j = 0; j < 4; j++) {
        accg[i][j] = __builtin_amdgcn_mfma_f32_16x16x32_bf16(a[i], bg[j], accg[i][j], 0, 0, 0);
        accu[i][j] = __builtin_amdgcn_mfma_f32_16x16x32_bf16(a[i], bu[j], accu[i][j], 0, 0, 0);
      }
    __syncthreads();
  }

  const int rgrp = lane >> 4;
#pragma unroll
  for (int j = 0; j < 4; j++) {
    int n = (int)n0 + wn * 64 + j * 16 + ln;
    float gs = gscale[n], us = uscale[n];
#pragma unroll
    for (int i = 0; i < 4; i++) {
      int rowb = (int)m0 + wm * 64 + i * 16 + rgrp * 4;
#pragma unroll
      for (int r = 0; r < 4; r++) {
        float g = accg[i][j][r] * gs;
        float u = accu[i][j][r] * us;
        float h = g * (1.0f / (1.0f + __expf(-g))) * u;
        hidden[(size_t)(rowb + r) * 16384 + n] = f2bf(h);
      }
    }
  }
}

// ---------------- GEMM2: hidden @ down^T, scale epilogue -> fp32 out ----------------
// Dense B: (32768,16,64). Chunked B: (65536,32,128).
__global__ __launch_bounds__(256, 3) void k_mlp_gemm2(
    const char* __restrict__ hq, const char* __restrict__ dw,
    const float* __restrict__ dscale, float* __restrict__ out,
    size_t bRow, int bChunk, int bStep) {
  __shared__ __align__(16) unsigned short sA[4096], sB[4096];
  const int tid = threadIdx.x, lane = tid & 63, wid = tid >> 6;
  const int mt = blockIdx.x & 31, nt = blockIdx.x >> 5;
  const size_t m0 = (size_t)mt * 128, n0 = (size_t)nt * 128;

  const int q0 = wid * 64 + lane, q1 = q0 + 256;
  const int r0 = q0 >> 2, c0 = (q0 & 3) ^ ((q0 >> 3) & 3);
  const int r1 = q1 >> 2, c1 = (q1 & 3) ^ ((q1 >> 3) & 3);

  const char* srcA0 = hq + (m0 + r0) * 32768 + c0 * 16;
  const char* srcA1 = hq + (m0 + r1) * 32768 + c1 * 16;
  const char* srcB0 = dw + (n0 + r0) * bRow + (size_t)c0 * bChunk;
  const char* srcB1 = dw + (n0 + r1) * bRow + (size_t)c1 * bChunk;

  char* dA0 = (char*)sA + wid * 1024; char* dA1 = dA0 + 4096;
  char* dB0 = (char*)sB + wid * 1024; char* dB1 = dB0 + 4096;

  const int wm = wid >> 1, wn = wid & 1, ln = lane & 15;
  const int slot = ((lane >> 4) ^ ((ln >> 1) & 3)) * 16;
  const char* aBase = (const char*)sA + (size_t)(wm * 64 + ln) * 64 + slot;
  const char* bBase = (const char*)sB + (size_t)(wn * 64 + ln) * 64 + slot;

  f32x4 acc[4][4] = {};

  for (int kt = 0; kt < 16384; kt += 32) {
    async_cp16(dA0, srcA0); async_cp16(dA1, srcA1);
    async_cp16(dB0, srcB0); async_cp16(dB1, srcB1);
    srcA0 += 64; srcA1 += 64; srcB0 += bStep; srcB1 += bStep;
    __syncthreads();
    short8 a[4], b[4];
#pragma unroll
    for (int i = 0; i < 4; i++) {
      a[i] = *(const short8*)(aBase + i * 1024);
      b[i] = *(const short8*)(bBase + i * 1024);
    }
#pragma unroll
    for (int i = 0; i < 4; i++)
#pragma unroll
      for (int j = 0; j < 4; j++)
        acc[i][j] = __builtin_amdgcn_mfma_f32_16x16x32_bf16(a[i], b[j], acc[i][j], 0, 0, 0);
    __syncthreads();
  }

  const int rgrp = lane >> 4;
#pragma unroll
  for (int j = 0; j < 4; j++) {
    int n = (int)n0 + wn * 64 + j * 16 + ln;
    float ds = dscale[n];
#pragma unroll
    for (int i = 0; i < 4; i++) {
      int rowb = (int)m0 + wm * 64 + i * 16 + rgrp * 4;
#pragma unroll
      for (int r = 0; r < 4; r++)
        out[(size_t)(rowb + r) * 4096 + n] = acc[i][j][r] * ds;
    }
  }
}

extern "C" void kernel_launch(void* const* d_in, const int* in_sizes, int n_in,
                              void* d_out, int out_size, void* d_ws, size_t ws_size,
                              hipStream_t stream) {
  (void)in_sizes; (void)n_in; (void)out_size;
  const float* x      = (const float*)d_in[0];
  float*       gate_w = (float*)d_in[1];
  const float* gscale = (const float*)d_in[2];
  float*       up_w   = (float*)d_in[3];
  const float* uscale = (const float*)d_in[4];
  float*       down_w = (float*)d_in[5];
  const float* dscale = (const float*)d_in[6];
  float*       out    = (float*)d_out;

  const size_t MB128 = 134217728ull;
  // ws layout (dense path): hidden[0,128M) gq[128M,256M) uq[256M,384M) dq[384M,512M) sums[512M,+24)
  // ws layout (fallback):   hidden[0,128M) sums[128M,+24); weights quantized in-place (chunked)
  const bool dense = ws_size >= 4 * MB128 + 24;
  unsigned short* hidden = (unsigned short*)d_ws;
  unsigned short* gq = (unsigned short*)((char*)d_ws + 1 * MB128);
  unsigned short* uq = (unsigned short*)((char*)d_ws + 2 * MB128);
  unsigned short* dq = (unsigned short*)((char*)d_ws + 3 * MB128);
  double* sums = (double*)((char*)d_ws + (dense ? 4 * MB128 : MB128));
  // xq bf16 [4096][4096] (32 MiB) lives in d_out; dead before GEMM2 overwrites it
  unsigned short* xq = (unsigned short*)d_out;

  hipMemsetAsync(sums, 0, 3 * sizeof(double), stream);
  k_absmean<<<4096, 256, 0, stream>>>((const float4*)gate_w, 16777216, sums + 0);
  k_absmean<<<4096, 256, 0, stream>>>((const float4*)up_w,   16777216, sums + 1);
  k_absmean<<<4096, 256, 0, stream>>>((const float4*)down_w, 16777216, sums + 2);

  const double inv_n = 1.0 / 67108864.0;
  k_quant_x<<<2048, 256, 0, stream>>>((const float4*)x, xq, 2097152);

  if (dense) {
    k_quant_w_dense<<<4096, 256, 0, stream>>>(gate_w, gq, 8388608, sums + 0, inv_n);
    k_quant_w_dense<<<4096, 256, 0, stream>>>(up_w,   uq, 8388608, sums + 1, inv_n);
    k_quant_w_dense<<<4096, 256, 0, stream>>>(down_w, dq, 8388608, sums + 2, inv_n);
    k_mlp_gemm1<<<4096, 256, 0, stream>>>((const char*)xq, (const char*)gq, (const char*)uq,
                                          gscale, uscale, hidden, 8192, 16, 64);
    k_mlp_gemm2<<<1024, 256, 0, stream>>>((const char*)hidden, (const char*)dq,
                                          dscale, out, 32768, 16, 64);
  } else {
    k_quant_w_inplace<<<4096, 256, 0, stream>>>(gate_w, 8388608, sums + 0, inv_n);
    k_quant_w_inplace<<<4096, 256, 0, stream>>>(up_w,   8388608, sums + 1, inv_n);
    k_quant_w_inplace<<<4096, 256, 0, stream>>>(down_w, 8388608, sums + 2, inv_n);
    k_mlp_gemm1<<<4096, 256, 0, stream>>>((const char*)xq, (const char*)gate_w,
                                          (const char*)up_w, gscale, uscale, hidden,
                                          16384, 32, 128);
    k_mlp_gemm2<<<1024, 256, 0, stream>>>((const char*)hidden, (const char*)down_w,
                                          dscale, out, 65536, 32, 128);
  }
}

// Round 4
// 2502.608 us; speedup vs baseline: 1.1027x; 1.1027x over previous
//
#include <hip/hip_runtime.h>

typedef __attribute__((ext_vector_type(8))) short short8;
typedef __attribute__((ext_vector_type(4))) float f32x4;

#define AS1 __attribute__((address_space(1)))
#define AS3 __attribute__((address_space(3)))

__device__ __forceinline__ void async_cp16(char* lds_dst, const char* g_src) {
  __builtin_amdgcn_global_load_lds((const AS1 void*)g_src, (AS3 void*)lds_dst, 16, 0, 0);
}

__device__ __forceinline__ unsigned short f2bf(float f) {
  unsigned int x = __float_as_uint(f);
  x += 0x7FFFu + ((x >> 16) & 1u);
  return (unsigned short)(x >> 16);
}

// ---------------- fused pass 1: sum(|w|) for all 3 weight matrices ----------------
// grid 12288: blocks [0,4096)->w0, [4096,8192)->w1, [8192,12288)->w2
__global__ void k_sums(const float4* __restrict__ w0, const float4* __restrict__ w1,
                       const float4* __restrict__ w2, double* __restrict__ out) {
  const int seg = blockIdx.x >> 12, bid = blockIdx.x & 4095;
  const float4* w = (seg == 0) ? w0 : (seg == 1) ? w1 : w2;
  double s = 0.0;
  const int stride = 4096 * 256;
  for (int i = bid * 256 + threadIdx.x; i < 16777216; i += stride) {
    float4 v = w[i];
    s += (double)(fabsf(v.x) + fabsf(v.y) + fabsf(v.z) + fabsf(v.w));
  }
  for (int off = 32; off > 0; off >>= 1) s += __shfl_down(s, off);
  __shared__ double ss[4];
  int lane = threadIdx.x & 63, wid = threadIdx.x >> 6;
  if (lane == 0) ss[wid] = s;
  __syncthreads();
  if (threadIdx.x == 0) atomicAdd(out + seg, ss[0] + ss[1] + ss[2] + ss[3]);
}

// ---------------- fused pass 2: quantize 3 weights + convert x ----------------
// grid 13312: [0,4096)->w0, [4096,8192)->w1, [8192,12288)->w2, [12288,13312)->x
// dense==1: ternary bf16 -> dst (contiguous). dense==0: in-place chunked
// (chunk c -> 8 bf16 in bytes [32c,32c+16); write subset of own read -> race-free).
__global__ void k_prep(const float4* __restrict__ x, unsigned short* __restrict__ xq,
                       float* __restrict__ w0, float* __restrict__ w1, float* __restrict__ w2,
                       unsigned short* __restrict__ d0, unsigned short* __restrict__ d1,
                       unsigned short* __restrict__ d2,
                       const double* __restrict__ sums, double inv_n, int dense) {
  const int seg = blockIdx.x >> 12;
  if (seg < 3) {
    float* w = (seg == 0) ? w0 : (seg == 1) ? w1 : w2;
    unsigned short* dst = (seg == 0) ? d0 : (seg == 1) ? d1 : d2;
    const float thr = (float)(sums[seg] * 0.7 * inv_n);
    const int bid = blockIdx.x & 4095, stride = 4096 * 256;
    for (int c = bid * 256 + threadIdx.x; c < 8388608; c += stride) {
      float4 a, b;
      if (dense) {
        const float4* w4 = (const float4*)w;
        a = w4[(size_t)c * 2]; b = w4[(size_t)c * 2 + 1];
      } else {
        const float4* src = (const float4*)((const char*)w + (size_t)c * 32);
        a = src[0]; b = src[1];
      }
      float v[8] = {a.x, a.y, a.z, a.w, b.x, b.y, b.z, b.w};
      short8 o;
#pragma unroll
      for (int e = 0; e < 8; e++) {
        unsigned int bits = __float_as_uint(v[e]);
        unsigned short q = (fabsf(v[e]) > thr)
                               ? (unsigned short)(0x3F80u | ((bits >> 16) & 0x8000u))
                               : (unsigned short)0;
        o[e] = (short)q;
      }
      if (dense) *(short8*)(dst + (size_t)c * 8) = o;
      else       *(short8*)((char*)w + (size_t)c * 32) = o;
    }
  } else {
    const int bid = blockIdx.x & 4095, stride = 1024 * 256;
    for (int c = bid * 256 + threadIdx.x; c < 2097152; c += stride) {
      float4 a = x[(size_t)c * 2], b = x[(size_t)c * 2 + 1];
      float v[8] = {a.x, a.y, a.z, a.w, b.x, b.y, b.z, b.w};
      short8 o;
#pragma unroll
      for (int e = 0; e < 8; e++) o[e] = (short)f2bf(v[e]);
      *(short8*)(xq + (size_t)c * 8) = o;
    }
  }
}

// =================================================================
// Deep-pipelined GEMMs: ring-4 LDS K-tile buffers (BK=32), counted
// vmcnt(4), stage distance 2 tiles (stage target never aliases the
// buffer being read: (t+2)&3 != t&3), 16 MFMA per barrier, setprio
// around MFMA clusters. Swizzle: LDS slot s of row r holds source
// k-chunk s^((r>>1)&3); reads use slot kq^((ln>>1)&3) (0 conflicts,
// HW-verified round 2).
// =================================================================

// ---------------- GEMM1: 256M x 128N tiles, dual gate/up acc, SiLU fused ----------------
__global__ __launch_bounds__(512, 2) void k_gemm1_8p(
    const char* __restrict__ xq, const char* __restrict__ gw, const char* __restrict__ uw,
    const float* __restrict__ gscale, const float* __restrict__ uscale,
    unsigned short* __restrict__ hidden, size_t rowB, int chunkB, int stepB) {
  __shared__ __align__(16) char lds[131072];  // 4 bufs x (A 16K | G 8K | U 8K)
  const int tid = threadIdx.x, lane = tid & 63, wid = tid >> 6;
  const int bidp = (blockIdx.x & 7) * 256 + (blockIdx.x >> 3);  // bijective, 2048%8==0
  const int mt = bidp & 15, nt = bidp >> 4;  // mt fast: same-nt blocks share B panel
  const size_t m0 = (size_t)mt * 256, n0 = (size_t)nt * 128;

  const int sr = tid >> 2;
  const int sc = (tid & 3) ^ ((sr >> 1) & 3);
  const char* srcA0 = xq + (m0 + sr) * 8192 + sc * 16;
  const char* srcA1 = xq + (m0 + 128 + sr) * 8192 + sc * 16;
  const char* srcG  = gw + (n0 + sr) * rowB + (size_t)sc * chunkB;
  const char* srcU  = uw + (n0 + sr) * rowB + (size_t)sc * chunkB;
  const unsigned ldA0 = tid * 16, ldA1 = 8192 + tid * 16;
  const unsigned ldG = 16384 + tid * 16, ldU = 24576 + tid * 16;

  // waves 4M x 2N; per-wave 64 rows x 64 true-n
  const int wm = wid >> 1, wn = wid & 1, ln = lane & 15;
  const int slot = ((lane >> 4) ^ ((ln >> 1) & 3)) * 16;
  unsigned aOff[4], gOff[4], uOff[4];
#pragma unroll
  for (int i = 0; i < 4; i++) aOff[i] = (wm * 64 + i * 16 + ln) * 64 + slot;
#pragma unroll
  for (int j = 0; j < 4; j++) {
    gOff[j] = 16384 + (wn * 64 + j * 16 + ln) * 64 + slot;
    uOff[j] = 24576 + (wn * 64 + j * 16 + ln) * 64 + slot;
  }

  f32x4 accg[4][4] = {}; f32x4 accu[4][4] = {};

#define G1_STP1(BB) { async_cp16(lds + (BB) + ldA0, srcA0); async_cp16(lds + (BB) + ldG, srcG); }
#define G1_STP2(BB) { async_cp16(lds + (BB) + ldA1, srcA1); async_cp16(lds + (BB) + ldU, srcU); }
#define G1_ADV()    { srcA0 += 64; srcA1 += 64; srcG += stepB; srcU += stepB; }

  G1_STP1(0) G1_STP2(0) G1_ADV();
  G1_STP1(32768) G1_STP2(32768) G1_ADV();
  asm volatile("s_waitcnt vmcnt(4)" ::: "memory");
  __builtin_amdgcn_s_barrier();

  for (int q = 0; q < 32; ++q) {
#pragma unroll
    for (int j4 = 0; j4 < 4; ++j4) {
      const int t = q * 4 + j4;
      const unsigned RB = (unsigned)(t & 3) * 32768;
      const unsigned SB = (unsigned)((t + 2) & 3) * 32768;
      const bool st = t < 126;
      // phase 1: gate quadrant
      short8 a[4], g[4];
#pragma unroll
      for (int i = 0; i < 4; i++) a[i] = *(const short8*)(lds + RB + aOff[i]);
#pragma unroll
      for (int j = 0; j < 4; j++) g[j] = *(const short8*)(lds + RB + gOff[j]);
      if (st) { G1_STP1(SB); }
      __builtin_amdgcn_s_barrier();
      __builtin_amdgcn_s_setprio(1);
#pragma unroll
      for (int i = 0; i < 4; i++)
#pragma unroll
        for (int j = 0; j < 4; j++)
          accg[i][j] = __builtin_amdgcn_mfma_f32_16x16x32_bf16(a[i], g[j], accg[i][j], 0, 0, 0);
      __builtin_amdgcn_s_setprio(0);
      // phase 2: up quadrant (reuses a[])
      short8 u[4];
#pragma unroll
      for (int j = 0; j < 4; j++) u[j] = *(const short8*)(lds + RB + uOff[j]);
      if (st) { G1_STP2(SB); }
      G1_ADV();
      if (st) { asm volatile("s_waitcnt vmcnt(4)" ::: "memory"); }
      else    { asm volatile("s_waitcnt vmcnt(0)" ::: "memory"); }
      __builtin_amdgcn_s_barrier();
      __builtin_amdgcn_s_setprio(1);
#pragma unroll
      for (int i = 0; i < 4; i++)
#pragma unroll
        for (int j = 0; j < 4; j++)
          accu[i][j] = __builtin_amdgcn_mfma_f32_16x16x32_bf16(a[i], u[j], accu[i][j], 0, 0, 0);
      __builtin_amdgcn_s_setprio(0);
    }
  }

  // fused SiLU epilogue (register-local: g and u in same thread)
  const int rg = lane >> 4;
#pragma unroll
  for (int j = 0; j < 4; j++) {
    int n = (int)n0 + wn * 64 + j * 16 + ln;
    float gs = gscale[n], us = uscale[n];
#pragma unroll
    for (int i = 0; i < 4; i++) {
      int row = (int)m0 + wm * 64 + i * 16 + rg * 4;
#pragma unroll
      for (int r = 0; r < 4; r++) {
        float gv = accg[i][j][r] * gs;
        float uv = accu[i][j][r] * us;
        float h = gv * (1.0f / (1.0f + __expf(-gv))) * uv;
        hidden[(size_t)(row + r) * 16384 + n] = f2bf(h);
      }
    }
  }
#undef G1_STP1
#undef G1_STP2
#undef G1_ADV
}

// ---------------- GEMM2: 256x256 tiles, dscale epilogue -> fp32 out ----------------
__global__ __launch_bounds__(512, 2) void k_gemm2_8p(
    const char* __restrict__ hq, const char* __restrict__ dw,
    const float* __restrict__ dscale, float* __restrict__ out,
    size_t rowB, int chunkB, int stepB) {
  __shared__ __align__(16) char lds[131072];  // 4 bufs x (A 16K | B 16K)
  const int tid = threadIdx.x, lane = tid & 63, wid = tid >> 6;
  const int bidp = (blockIdx.x & 7) * 32 + (blockIdx.x >> 3);  // 256%8==0
  const int mt = bidp & 15, nt = bidp >> 4;
  const size_t m0 = (size_t)mt * 256, n0 = (size_t)nt * 256;

  const int sr = tid >> 2;
  const int sc = (tid & 3) ^ ((sr >> 1) & 3);
  const char* srcA0 = hq + (m0 + sr) * 32768 + sc * 16;
  const char* srcA1 = hq + (m0 + 128 + sr) * 32768 + sc * 16;
  const char* srcB0 = dw + (n0 + sr) * rowB + (size_t)sc * chunkB;
  const char* srcB1 = dw + (n0 + 128 + sr) * rowB + (size_t)sc * chunkB;
  const unsigned ldA0 = tid * 16, ldA1 = 8192 + tid * 16;
  const unsigned ldB0 = 16384 + tid * 16, ldB1 = 24576 + tid * 16;

  // waves 2M x 4N; per-wave 128 rows x 64 cols
  const int wm = wid >> 2, wn = wid & 3, ln = lane & 15;
  const int slot = ((lane >> 4) ^ ((ln >> 1) & 3)) * 16;
  unsigned aOff[8], bOff[4];
#pragma unroll
  for (int i = 0; i < 8; i++) aOff[i] = (wm * 128 + i * 16 + ln) * 64 + slot;
#pragma unroll
  for (int j = 0; j < 4; j++) bOff[j] = 16384 + (wn * 64 + j * 16 + ln) * 64 + slot;

  f32x4 acc[8][4] = {};

#define G2_STP1(BB) { async_cp16(lds + (BB) + ldA0, srcA0); async_cp16(lds + (BB) + ldB0, srcB0); }
#define G2_STP2(BB) { async_cp16(lds + (BB) + ldA1, srcA1); async_cp16(lds + (BB) + ldB1, srcB1); }
#define G2_ADV()    { srcA0 += 64; srcA1 += 64; srcB0 += stepB; srcB1 += stepB; }

  G2_STP1(0) G2_STP2(0) G2_ADV();
  G2_STP1(32768) G2_STP2(32768) G2_ADV();
  asm volatile("s_waitcnt vmcnt(4)" ::: "memory");
  __builtin_amdgcn_s_barrier();

  for (int q = 0; q < 128; ++q) {
#pragma unroll
    for (int j4 = 0; j4 < 4; ++j4) {
      const int t = q * 4 + j4;
      const unsigned RB = (unsigned)(t & 3) * 32768;
      const unsigned SB = (unsigned)((t + 2) & 3) * 32768;
      const bool st = t < 510;
      // phase 1: m-reps 0-3
      short8 a0[4], b[4];
#pragma unroll
      for (int i = 0; i < 4; i++) a0[i] = *(const short8*)(lds + RB + aOff[i]);
#pragma unroll
      for (int j = 0; j < 4; j++) b[j] = *(const short8*)(lds + RB + bOff[j]);
      if (st) { G2_STP1(SB); }
      __builtin_amdgcn_s_barrier();
      __builtin_amdgcn_s_setprio(1);
#pragma unroll
      for (int i = 0; i < 4; i++)
#pragma unroll
        for (int j = 0; j < 4; j++)
          acc[i][j] = __builtin_amdgcn_mfma_f32_16x16x32_bf16(a0[i], b[j], acc[i][j], 0, 0, 0);
      __builtin_amdgcn_s_setprio(0);
      // phase 2: m-reps 4-7 (reuses b[])
      short8 a1[4];
#pragma unroll
      for (int i = 0; i < 4; i++) a1[i] = *(const short8*)(lds + RB + aOff[4 + i]);
      if (st) { G2_STP2(SB); }
      G2_ADV();
      if (st) { asm volatile("s_waitcnt vmcnt(4)" ::: "memory"); }
      else    { asm volatile("s_waitcnt vmcnt(0)" ::: "memory"); }
      __builtin_amdgcn_s_barrier();
      __builtin_amdgcn_s_setprio(1);
#pragma unroll
      for (int i = 0; i < 4; i++)
#pragma unroll
        for (int j = 0; j < 4; j++)
          acc[4 + i][j] = __builtin_amdgcn_mfma_f32_16x16x32_bf16(a1[i], b[j], acc[4 + i][j], 0, 0, 0);
      __builtin_amdgcn_s_setprio(0);
    }
  }

  const int rg = lane >> 4;
#pragma unroll
  for (int j = 0; j < 4; j++) {
    int n = (int)n0 + wn * 64 + j * 16 + ln;
    float ds = dscale[n];
#pragma unroll
    for (int i = 0; i < 8; i++) {
      int row = (int)m0 + wm * 128 + i * 16 + rg * 4;
#pragma unroll
      for (int r = 0; r < 4; r++)
        out[(size_t)(row + r) * 4096 + n] = acc[i][j][r] * ds;
    }
  }
#undef G2_STP1
#undef G2_STP2
#undef G2_ADV
}

extern "C" void kernel_launch(void* const* d_in, const int* in_sizes, int n_in,
                              void* d_out, int out_size, void* d_ws, size_t ws_size,
                              hipStream_t stream) {
  (void)in_sizes; (void)n_in; (void)out_size;
  const float* x      = (const float*)d_in[0];
  float*       gate_w = (float*)d_in[1];
  const float* gscale = (const float*)d_in[2];
  float*       up_w   = (float*)d_in[3];
  const float* uscale = (const float*)d_in[4];
  float*       down_w = (float*)d_in[5];
  const float* dscale = (const float*)d_in[6];
  float*       out    = (float*)d_out;

  const size_t MB128 = 134217728ull;
  const bool dense = ws_size >= 4 * MB128 + 24;
  unsigned short* hidden = (unsigned short*)d_ws;
  unsigned short* gq = (unsigned short*)((char*)d_ws + 1 * MB128);
  unsigned short* uq = (unsigned short*)((char*)d_ws + 2 * MB128);
  unsigned short* dq = (unsigned short*)((char*)d_ws + 3 * MB128);
  double* sums = (double*)((char*)d_ws + (dense ? 4 * MB128 : MB128));
  unsigned short* xq = (unsigned short*)d_out;  // dead before GEMM2 writes out

  hipMemsetAsync(sums, 0, 3 * sizeof(double), stream);
  k_sums<<<12288, 256, 0, stream>>>((const float4*)gate_w, (const float4*)up_w,
                                    (const float4*)down_w, sums);

  const double inv_n = 1.0 / 67108864.0;
  k_prep<<<13312, 256, 0, stream>>>((const float4*)x, xq, gate_w, up_w, down_w,
                                    gq, uq, dq, sums, inv_n, dense ? 1 : 0);

  if (dense) {
    k_gemm1_8p<<<2048, 512, 0, stream>>>((const char*)xq, (const char*)gq, (const char*)uq,
                                         gscale, uscale, hidden, 8192, 16, 64);
    k_gemm2_8p<<<256, 512, 0, stream>>>((const char*)hidden, (const char*)dq,
                                        dscale, out, 32768, 16, 64);
  } else {
    k_gemm1_8p<<<2048, 512, 0, stream>>>((const char*)xq, (const char*)gate_w,
                                         (const char*)up_w, gscale, uscale, hidden,
                                         16384, 32, 128);
    k_gemm2_8p<<<256, 512, 0, stream>>>((const char*)hidden, (const char*)down_w,
                                        dscale, out, 65536, 32, 128);
  }
}